// Round 18
// baseline (132.203 us; speedup 1.0000x reference)
//
#include <hip/hip_runtime.h>

// out[b, w, j] = sum_p x[b,j,p] * weight[j,p,w] + bias[j,w]
// x: [B,M,P] f32, weight: [M,P,W] f32, bias: [M,W] f32, out: [B,W,M] f32
// B=128, M=10000, P=64, W=24.
//
// Round-18: r16 structure (NCH=4, grid 1250, separate obuf, 2 barriers per
// chunk) tuned to ACTUALLY fit 64 VGPR so (1024,8) gives 8 waves/SIMD =
// 32 waves/CU without spilling (r17 forced 64 with a ~70-reg live set ->
// spill -> 126.8us). Fix: no cross-phase nx prefetch; chunk c+1 global
// loads are issued at the top of the drain phase (in flight during the
// obuf drain stores) and ds_written at its end -- nx never spans the MFMA
// region. Peak live ~50. Latency hiding moves from reg-pipelining to TLP.

constexpr int B  = 128;
constexpr int M  = 10000;
constexpr int P  = 64;
constexpr int W  = 24;

constexpr int JT  = 16;    // j per block = waves per block
constexpr int BH  = 16;    // b per chunk (one M-tile)
constexpr int NCH = 4;     // chunks per block -> 64 b per block
constexpr int NT  = 1024;  // 16 waves
constexpr int NWG = (M / JT) * (B / (BH * NCH));  // 1250

using bf8   = __attribute__((ext_vector_type(8))) __bf16;
using bf4   = __attribute__((ext_vector_type(4))) __bf16;
using f32x4 = __attribute__((ext_vector_type(4))) float;

__global__ __launch_bounds__(NT, 8) void pcl_kernel(
    const float* __restrict__ x, const float* __restrict__ wgt,
    const float* __restrict__ bias, float* __restrict__ out) {
  // xsh:  bf16 [b 16][j 16][p 64], p-chunks (8p=16B) at idx (p>>3)^(b&7).
  // obuf: f32 [jl*16+b][w 25pad] = 25,600 B, separate region.
  __shared__ __align__(16) char smem[58368];
  unsigned short* xsh  = reinterpret_cast<unsigned short*>(smem);
  float*          obuf = reinterpret_cast<float*>(smem + 32768);

  const int t = threadIdx.x;

  // bijective XCD swizzle (m204): 1250 = 8*156 + 2; consecutive wgid on one
  // XCD share jt (2 b-halves) -> weight L2 reuse.
  const int orig = blockIdx.x;
  const int xcd  = orig & 7;
  const int idx  = orig >> 3;
  const int wgid = (xcd < 2 ? xcd * 157 : 314 + (xcd - 2) * 156) + idx;
  const int jt    = wgid >> 1;
  const int bbase = (wgid & 1) * (BH * NCH);  // 0 or 64
  const int j0    = jt * JT;

  const int wk   = t >> 6;     // wave = local j
  const int lane = t & 63;
  const int col  = lane & 15;  // A-row(b) / B-col(w) / D-col(w)
  const int kg   = lane >> 4;  // k-group
  const int j    = j0 + wk;    // this wave's j

  // per-thread xsh-staging geometry (fixed across chunks)
  const int gb  = t >> 8;          // staged b base (i-th load adds 4i)
  const int gj  = (t >> 4) & 15;   // staged j
  const int gc2 = t & 15;          // fp32 16B chunk

  // ---- stage chunk 0: issue x loads first (critical path) ----
  float4 nx[4];
#pragma unroll
  for (int i = 0; i < 4; ++i) {
    nx[i] = *reinterpret_cast<const float4*>(
        x + ((size_t)(bbase + gb + 4 * i) * M + j0 + gj) * P + 4 * gc2);
  }

  // bias (per-lane, hoisted)
  float bv[2];
#pragma unroll
  for (int nt = 0; nt < 2; ++nt) {
    const int w = nt * 16 + col;
    bv[nt] = (w < W) ? bias[(size_t)j * W + w] : 0.0f;
  }

  // ---- weight B-frags -> 16 VGPRs (once per block) ----
  bf8 bfr[2][2];
#pragma unroll
  for (int ks = 0; ks < 2; ++ks) {
#pragma unroll
    for (int nt = 0; nt < 2; ++nt) {
      const int w     = nt * 16 + col;
      const bool ok   = (w < W);
      const float* wp = wgt + (size_t)j * (P * W) +
                        (size_t)(ks * 32 + kg * 8) * W + (ok ? w : 0);
      bf8 v;
#pragma unroll
      for (int e = 0; e < 8; ++e) v[e] = (__bf16)wp[(size_t)e * W];
      if (!ok) {
#pragma unroll
        for (int e = 0; e < 8; ++e) v[e] = (__bf16)0.0f;
      }
      bfr[ks][nt] = v;
    }
  }

  // write chunk 0 into swizzled xsh
#pragma unroll
  for (int i = 0; i < 4; ++i) {
    const int b  = gb + 4 * i;
    const int ss = (gc2 >> 1) ^ (b & 7);
    bf4 v;
    v[0] = (__bf16)nx[i].x; v[1] = (__bf16)nx[i].y;
    v[2] = (__bf16)nx[i].z; v[3] = (__bf16)nx[i].w;
    *reinterpret_cast<bf4*>(xsh + (((b << 4) + gj) << 6) + (ss << 3) +
                            ((gc2 & 1) << 2)) = v;
  }
  __syncthreads();  // xsh chunk 0 visible

  for (int c = 0; c < NCH; ++c) {
    // ---- compute: 2 A ds_read_b128 + 4 MFMA ----
    f32x4 acc[2];
#pragma unroll
    for (int nt = 0; nt < 2; ++nt)
      acc[nt] = f32x4{bv[nt], bv[nt], bv[nt], bv[nt]};

#pragma unroll
    for (int ks = 0; ks < 2; ++ks) {
      const int cc = ks * 4 + kg;
      const bf8 af = *reinterpret_cast<const bf8*>(
          xsh + (((col << 4) + wk) << 6) + ((cc ^ (col & 7)) << 3));
#pragma unroll
      for (int nt = 0; nt < 2; ++nt)
        acc[nt] = __builtin_amdgcn_mfma_f32_16x16x32_bf16(
            af, bfr[ks][nt], acc[nt], 0, 0, 0);
    }

    // ---- obuf transpose write (separate region: no barrier needed) ----
#pragma unroll
    for (int nt = 0; nt < 2; ++nt) {
      const int w = nt * 16 + col;
      if (w < W) {
#pragma unroll
        for (int reg = 0; reg < 4; ++reg)
          obuf[(wk * 16 + kg * 4 + reg) * 25 + w] = acc[nt][reg];
      }
    }
    __syncthreads();  // obuf visible; all compute(c) xsh reads done

    // ---- issue chunk c+1 x loads (overlap the drain stores) ----
    if (c < NCH - 1) {
      const int b0n = bbase + (c + 1) * BH;
#pragma unroll
      for (int i = 0; i < 4; ++i) {
        nx[i] = *reinterpret_cast<const float4*>(
            x + ((size_t)(b0n + gb + 4 * i) * M + j0 + gj) * P + 4 * gc2);
      }
    }

    // ---- drain(c): 64B j-run float4 stores ----
    const int b0c = bbase + c * BH;
#pragma unroll
    for (int it = 0; it < 2; ++it) {
      const int d = t + it * NT;
      if (d < 1536) {
        const int jq   = d & 3;
        const int rest = d >> 2;        // 0..383
        const int w    = rest % 24;
        const int br   = rest / 24;     // 0..15
        float4 o;
        o.x = obuf[((4 * jq + 0) * 16 + br) * 25 + w];
        o.y = obuf[((4 * jq + 1) * 16 + br) * 25 + w];
        o.z = obuf[((4 * jq + 2) * 16 + br) * 25 + w];
        o.w = obuf[((4 * jq + 3) * 16 + br) * 25 + w];
        *reinterpret_cast<float4*>(
            out + ((size_t)(b0c + br) * W + w) * M + j0 + 4 * jq) = o;
      }
    }

    // ---- convert + write chunk c+1 into xsh ----
    if (c < NCH - 1) {
#pragma unroll
      for (int i = 0; i < 4; ++i) {
        const int b  = gb + 4 * i;
        const int ss = (gc2 >> 1) ^ (b & 7);
        bf4 v;
        v[0] = (__bf16)nx[i].x; v[1] = (__bf16)nx[i].y;
        v[2] = (__bf16)nx[i].z; v[3] = (__bf16)nx[i].w;
        *reinterpret_cast<bf4*>(xsh + (((b << 4) + gj) << 6) + (ss << 3) +
                                ((gc2 & 1) << 2)) = v;
      }
      __syncthreads();  // xsh(c+1) visible; obuf drain reads done
    }
  }
}

extern "C" void kernel_launch(void* const* d_in, const int* in_sizes, int n_in,
                              void* d_out, int out_size, void* d_ws, size_t ws_size,
                              hipStream_t stream) {
  const float* x    = (const float*)d_in[0];
  const float* wgt  = (const float*)d_in[1];
  const float* bias = (const float*)d_in[2];
  float* out        = (float*)d_out;

  dim3 grid(NWG);  // 1250
  dim3 block(NT);  // 1024
  hipLaunchKernelGGL(pcl_kernel, grid, block, 0, stream, x, wgt, bias, out);
}

// Round 19
// 111.649 us; speedup vs baseline: 1.1841x; 1.1841x over previous
//
#include <hip/hip_runtime.h>

// out[b, w, j] = sum_p x[b,j,p] * weight[j,p,w] + bias[j,w]
// x: [B,M,P] f32, weight: [M,P,W] f32, bias: [M,W] f32, out: [B,W,M] f32
// B=128, M=10000, P=64, W=24.
//
// Round-19 = round-15 verbatim (best: 111.8us). r16 (barrier restructure):
// neutral. r17/r18 ((1024,8) VGPR squeeze): regressed -- allocator spills
// around the MFMA+staging live set (3rd confirmation: r3, r10, r17/18).
// Structure: NT=1024, one j per wave, weights in 16 VGPR B-frags, x staged
// to 32K swizzled bf16 LDS (obuf overlays between chunks), chunk c+1 reg-
// prefetch, MFMA 16x16x32_bf16, obuf transpose -> 64B j-run f4 stores,
// bijective XCD swizzle. Implied BW ~5.1 TB/s = 81% of m13 copy ceiling.

constexpr int B  = 128;
constexpr int M  = 10000;
constexpr int P  = 64;
constexpr int W  = 24;

constexpr int JT  = 16;    // j per block = waves per block
constexpr int BH  = 16;    // b per chunk (one M-tile)
constexpr int NCH = 4;     // chunks per block -> 64 b per block
constexpr int NT  = 1024;  // 16 waves
constexpr int NWG = (M / JT) * (B / (BH * NCH));  // 1250

using bf8   = __attribute__((ext_vector_type(8))) __bf16;
using bf4   = __attribute__((ext_vector_type(4))) __bf16;
using f32x4 = __attribute__((ext_vector_type(4))) float;

__global__ __launch_bounds__(NT, 4) void pcl_kernel(
    const float* __restrict__ x, const float* __restrict__ wgt,
    const float* __restrict__ bias, float* __restrict__ out) {
  // xsh: bf16 [b 16][j 16][p 64], p-chunks (8 p = 16B) at idx (p>>3)^(b&7).
  // obuf: f32 [jl*16+b][w 25pad] = 25,600 B, overlays xsh between chunks.
  __shared__ __align__(16) char smem[32768];
  unsigned short* xsh  = reinterpret_cast<unsigned short*>(smem);
  float*          obuf = reinterpret_cast<float*>(smem);

  const int t = threadIdx.x;

  // bijective XCD swizzle (m204): 1250 = 8*156 + 2; consecutive wgid on one
  // XCD share jt (2 b-halves) -> weight L2 reuse.
  const int orig = blockIdx.x;
  const int xcd  = orig & 7;
  const int idx  = orig >> 3;
  const int wgid = (xcd < 2 ? xcd * 157 : 314 + (xcd - 2) * 156) + idx;
  const int jt    = wgid >> 1;
  const int bbase = (wgid & 1) * (BH * NCH);  // 0 or 64
  const int j0    = jt * JT;

  const int wk   = t >> 6;     // wave = local j
  const int lane = t & 63;
  const int col  = lane & 15;  // A-row(b) / B-col(w) / D-col(w)
  const int kg   = lane >> 4;  // k-group
  const int j    = j0 + wk;    // this wave's j

  // bias (per-lane, hoisted)
  float bv[2];
#pragma unroll
  for (int nt = 0; nt < 2; ++nt) {
    const int w = nt * 16 + col;
    bv[nt] = (w < W) ? bias[(size_t)j * W + w] : 0.0f;
  }

  // ---- weight B-frags -> 16 VGPRs (once per block) ----
  bf8 bfr[2][2];
#pragma unroll
  for (int ks = 0; ks < 2; ++ks) {
#pragma unroll
    for (int nt = 0; nt < 2; ++nt) {
      const int w     = nt * 16 + col;
      const bool ok   = (w < W);
      const float* wp = wgt + (size_t)j * (P * W) +
                        (size_t)(ks * 32 + kg * 8) * W + (ok ? w : 0);
      bf8 v;
#pragma unroll
      for (int e = 0; e < 8; ++e) v[e] = (__bf16)wp[(size_t)e * W];
      if (!ok) {
#pragma unroll
        for (int e = 0; e < 8; ++e) v[e] = (__bf16)0.0f;
      }
      bfr[ks][nt] = v;
    }
  }

  // ---- prefetch x chunk 0 (4 f4/thread = 16 VGPR; 1KB/instr contiguous) --
  float4 nx[4];
#pragma unroll
  for (int i = 0; i < 4; ++i) {
    const int g  = t + i * NT;   // [b 16][j 16][p-f4 16]
    const int b  = g >> 8;
    const int jj = (g >> 4) & 15;
    const int c2 = g & 15;
    nx[i] = *reinterpret_cast<const float4*>(
        x + ((size_t)(bbase + b) * M + j0 + jj) * P + 4 * c2);
  }

  for (int c = 0; c < NCH; ++c) {
    if (c > 0) __syncthreads();  // obuf drain reads done -> xsh region free

    // ---- convert + write chunk c into swizzled xsh ----
#pragma unroll
    for (int i = 0; i < 4; ++i) {
      const int g  = t + i * NT;
      const int b  = g >> 8;
      const int jj = (g >> 4) & 15;
      const int c2 = g & 15;
      bf4 v;
      v[0] = (__bf16)nx[i].x; v[1] = (__bf16)nx[i].y;
      v[2] = (__bf16)nx[i].z; v[3] = (__bf16)nx[i].w;
      const int s = (c2 >> 1) ^ (b & 7);
      *reinterpret_cast<bf4*>(xsh + (((b << 4) + jj) << 6) + (s << 3) +
                              ((c2 & 1) << 2)) = v;
    }

    // ---- issue chunk c+1 global loads (land during compute/store) ----
    if (c < NCH - 1) {
      const int b0n = bbase + (c + 1) * BH;
#pragma unroll
      for (int i = 0; i < 4; ++i) {
        const int g  = t + i * NT;
        const int b  = g >> 8;
        const int jj = (g >> 4) & 15;
        const int c2 = g & 15;
        nx[i] = *reinterpret_cast<const float4*>(
            x + ((size_t)(b0n + b) * M + j0 + jj) * P + 4 * c2);
      }
    }

    __syncthreads();  // xsh visible

    // ---- compute: 2 A ds_read_b128 + 4 MFMA ----
    f32x4 acc[2];
#pragma unroll
    for (int nt = 0; nt < 2; ++nt)
      acc[nt] = f32x4{bv[nt], bv[nt], bv[nt], bv[nt]};

#pragma unroll
    for (int ks = 0; ks < 2; ++ks) {
      const int cc = ks * 4 + kg;
      const bf8 af = *reinterpret_cast<const bf8*>(
          xsh + (((col << 4) + wk) << 6) + ((cc ^ (col & 7)) << 3));
#pragma unroll
      for (int nt = 0; nt < 2; ++nt)
        acc[nt] = __builtin_amdgcn_mfma_f32_16x16x32_bf16(
            af, bfr[ks][nt], acc[nt], 0, 0, 0);
    }

    __syncthreads();  // xsh reads done before obuf overlay write

    // ---- obuf transpose write ----
#pragma unroll
    for (int nt = 0; nt < 2; ++nt) {
      const int w = nt * 16 + col;
      if (w < W) {
#pragma unroll
        for (int reg = 0; reg < 4; ++reg)
          obuf[(wk * 16 + kg * 4 + reg) * 25 + w] = acc[nt][reg];
      }
    }
    __syncthreads();  // obuf visible

    // ---- drain: 64B j-run float4 stores (1536 f4) ----
    const int b0c = bbase + c * BH;
#pragma unroll
    for (int it = 0; it < 2; ++it) {
      const int d = t + it * NT;
      if (d < 1536) {
        const int jq   = d & 3;
        const int rest = d >> 2;        // 0..383
        const int w    = rest % 24;
        const int br   = rest / 24;     // 0..15
        float4 o;
        o.x = obuf[((4 * jq + 0) * 16 + br) * 25 + w];
        o.y = obuf[((4 * jq + 1) * 16 + br) * 25 + w];
        o.z = obuf[((4 * jq + 2) * 16 + br) * 25 + w];
        o.w = obuf[((4 * jq + 3) * 16 + br) * 25 + w];
        *reinterpret_cast<float4*>(
            out + ((size_t)(b0c + br) * W + w) * M + j0 + 4 * jq) = o;
      }
    }
  }
}

extern "C" void kernel_launch(void* const* d_in, const int* in_sizes, int n_in,
                              void* d_out, int out_size, void* d_ws, size_t ws_size,
                              hipStream_t stream) {
  const float* x    = (const float*)d_in[0];
  const float* wgt  = (const float*)d_in[1];
  const float* bias = (const float*)d_in[2];
  float* out        = (float*)d_out;

  dim3 grid(NWG);  // 1250
  dim3 block(NT);  // 1024
  hipLaunchKernelGGL(pcl_kernel, grid, block, 0, stream, x, wgt, bias, out);
}